// Round 1
// baseline (107.954 us; speedup 1.0000x reference)
//
#include <hip/hip_runtime.h>
#include <hip/hip_bf16.h>

#define NROW 4096
#define D 128
#define TOT 8192  // 2N
// sqrt(2 * log2(e)) : fold temperature (x2) and ln->log2 into stored operand
#define PRESCALE 1.69864407f

typedef __attribute__((ext_vector_type(8))) short bf16x8;
typedef __attribute__((ext_vector_type(4))) float f32x4;

__device__ __forceinline__ float fast_exp2(float x) {
#if __has_builtin(__builtin_amdgcn_exp2f)
  return __builtin_amdgcn_exp2f(x);
#else
  return exp2f(x);
#endif
}
__device__ __forceinline__ float fast_log2(float x) {
#if __has_builtin(__builtin_amdgcn_logf)
  return __builtin_amdgcn_logf(x);
#else
  return log2f(x);
#endif
}

// round-to-nearest-even f32 -> bf16 bits (inputs are finite, no NaN concern)
__device__ __forceinline__ unsigned short f2bf(float x) {
  unsigned u = __float_as_uint(x);
  unsigned r = (u + 0x7fffu + ((u >> 16) & 1u)) >> 16;
  return (unsigned short)r;
}

// Kernel 1: per row r (one wave): L2-normalize emb_i[r], emb_j[r]; write
// prescaled bf16 rows to Zp[r] and Zp[r+N]; compute exact fp32 pos logit.
__global__ __launch_bounds__(256) void k_norm(
    const float* __restrict__ ei, const float* __restrict__ ej,
    unsigned short* __restrict__ Zp, float* __restrict__ pos) {
  int wid = threadIdx.x >> 6;
  int lane = threadIdx.x & 63;
  int r = blockIdx.x * 4 + wid;
  const float2 xi = *(const float2*)(ei + (size_t)r * D + lane * 2);
  const float2 xj = *(const float2*)(ej + (size_t)r * D + lane * 2);
  float si = xi.x * xi.x + xi.y * xi.y;
  float sj = xj.x * xj.x + xj.y * xj.y;
  float dd = xi.x * xj.x + xi.y * xj.y;
#pragma unroll
  for (int m = 32; m >= 1; m >>= 1) {
    si += __shfl_xor(si, m, 64);
    sj += __shfl_xor(sj, m, 64);
    dd += __shfl_xor(dd, m, 64);
  }
  float ri = rsqrtf(si); ri = ri * (1.5f - 0.5f * si * ri * ri);
  float rj = rsqrtf(sj); rj = rj * (1.5f - 0.5f * sj * rj * rj);
  unsigned short a0 = f2bf(xi.x * ri * PRESCALE);
  unsigned short a1 = f2bf(xi.y * ri * PRESCALE);
  unsigned short b0 = f2bf(xj.x * rj * PRESCALE);
  unsigned short b1 = f2bf(xj.y * rj * PRESCALE);
  unsigned wa = (unsigned)a0 | ((unsigned)a1 << 16);
  unsigned wb = (unsigned)b0 | ((unsigned)b1 << 16);
  ((unsigned*)(Zp + (size_t)r * D))[lane] = wa;
  ((unsigned*)(Zp + (size_t)(r + NROW) * D))[lane] = wb;
  if (lane == 0) pos[r] = 2.0f * dd * ri * rj;  // true logit (dot / T)
}

// Kernel 2: fused Z·Z^T + exp + row partial sums.
// Grid: 32 row-groups (256 rows each) x 32 col-slices (256 cols each).
// Block = 4 waves; wave owns 64 rows (A held in registers), streams 16-col
// B tiles; all 4 waves of a block share B addresses -> L1 reuse.
#define RG 32
#define CS 32
#define CPB (TOT / CS)  // 256
__global__ __launch_bounds__(256) void k_gemm(
    const unsigned short* __restrict__ Zp, float* __restrict__ rowsum) {
  int wid = threadIdx.x >> 6;
  int lane = threadIdx.x & 63;
  int lo = lane & 15, hi = lane >> 4;
  int rb = blockIdx.x & (RG - 1);
  int cs = blockIdx.x >> 5;
  int rowbase = rb * 256 + wid * 64;

  // A fragments: 64 rows x 128 k, held for the whole kernel (64 VGPRs)
  bf16x8 af[4][4];
#pragma unroll
  for (int g = 0; g < 4; ++g) {
    const unsigned short* za = Zp + (size_t)(rowbase + g * 16 + lo) * D + hi * 8;
#pragma unroll
    for (int kk = 0; kk < 4; ++kk)
      af[g][kk] = *(const bf16x8*)(za + kk * 32);
  }

  float sums[4][4];
#pragma unroll
  for (int g = 0; g < 4; ++g)
#pragma unroll
    for (int r = 0; r < 4; ++r) sums[g][r] = 0.0f;

  bool blkdiag = (cs == rb);
#pragma unroll 4
  for (int t = 0; t < CPB / 16; ++t) {
    int colbase = cs * CPB + t * 16;
    const unsigned short* zb = Zp + (size_t)(colbase + lo) * D + hi * 8;
    bf16x8 bf[4];
#pragma unroll
    for (int kk = 0; kk < 4; ++kk)
      bf[kk] = *(const bf16x8*)(zb + kk * 32);
    int gd = t - wid * 4;  // which g contains the diagonal (if any)
#pragma unroll
    for (int g = 0; g < 4; ++g) {
      f32x4 acc = {0.0f, 0.0f, 0.0f, 0.0f};
#pragma unroll
      for (int kk = 0; kk < 4; ++kk)
        acc = __builtin_amdgcn_mfma_f32_16x16x32_bf16(af[g][kk], bf[kk], acc, 0, 0, 0);
      // acc element r: row = rowbase+g*16+hi*4+r, col = colbase+lo
      if (blkdiag && g == gd) {
#pragma unroll
        for (int r = 0; r < 4; ++r) {
          float e = (lo == hi * 4 + r) ? 0.0f : fast_exp2(acc[r]);
          sums[g][r] += e;
        }
      } else {
#pragma unroll
        for (int r = 0; r < 4; ++r) sums[g][r] += fast_exp2(acc[r]);
      }
    }
  }

  // reduce the 16 column-slots per row, then atomically accumulate per row
#pragma unroll
  for (int g = 0; g < 4; ++g)
#pragma unroll
    for (int r = 0; r < 4; ++r) {
      float v = sums[g][r];
      v += __shfl_xor(v, 1, 64);
      v += __shfl_xor(v, 2, 64);
      v += __shfl_xor(v, 4, 64);
      v += __shfl_xor(v, 8, 64);
      if (lo == 0) atomicAdd(&rowsum[rowbase + g * 16 + hi * 4 + r], v);
    }
}

// Kernel 3: lse = ln(rowsum); loss = mean(lse) - mean(pos over anchors)
__global__ __launch_bounds__(256) void k_final(
    const float* __restrict__ rowsum, const float* __restrict__ pos,
    float* __restrict__ out) {
  int idx = blockIdx.x * 256 + (int)threadIdx.x;
  float lse = fast_log2(rowsum[idx]) * 0.69314718055994531f;
  float c = lse * (1.0f / (float)TOT);
  if (idx < NROW) c -= pos[idx] * (1.0f / (float)NROW);  // 2*pos/TOT
#pragma unroll
  for (int m = 32; m >= 1; m >>= 1) c += __shfl_xor(c, m, 64);
  __shared__ float ws[4];
  int wid = threadIdx.x >> 6, lane = threadIdx.x & 63;
  if (lane == 0) ws[wid] = c;
  __syncthreads();
  if (threadIdx.x == 0) atomicAdd(out, ws[0] + ws[1] + ws[2] + ws[3]);
}

extern "C" void kernel_launch(void* const* d_in, const int* in_sizes, int n_in,
                              void* d_out, int out_size, void* d_ws, size_t ws_size,
                              hipStream_t stream) {
  const float* ei = (const float*)d_in[0];
  const float* ej = (const float*)d_in[1];
  float* out = (float*)d_out;
  float* rowsum = (float*)d_ws;                                   // 8192 f32
  float* pos = (float*)((char*)d_ws + TOT * 4);                   // 4096 f32
  unsigned short* Zp =
      (unsigned short*)((char*)d_ws + TOT * 4 + NROW * 4);        // 8192x128 bf16

  hipMemsetAsync(out, 0, sizeof(float), stream);
  hipMemsetAsync(rowsum, 0, TOT * sizeof(float), stream);
  k_norm<<<NROW / 4, 256, 0, stream>>>(ei, ej, Zp, pos);
  k_gemm<<<RG * CS, 256, 0, stream>>>(Zp, rowsum);
  k_final<<<TOT / 256, 256, 0, stream>>>(rowsum, pos, out);
}